// Round 16
// baseline (186.477 us; speedup 1.0000x reference)
//
#include <hip/hip_runtime.h>
#include <stdint.h>

// Problem constants (B=2,S=1024,D=1024,F=4096,E=8)
#define T_TOK 2048
#define D_DIM 1024
#define F_DIM 4096
#define E_NUM 8
#define RPMAX 4096   // max padded rows at 256-alignment: 2048 + 8*255 -> 4096
#define BK 64

typedef __attribute__((ext_vector_type(8))) short bfx8;   // 8 bf16 (4 VGPR)
typedef __attribute__((ext_vector_type(4))) float fx4;    // MFMA accum / staging

__device__ __forceinline__ unsigned short f2bf(float f) {
  union { float f; uint32_t u; } v; v.f = f;
  uint32_t u = v.u;
  u += 0x7FFFu + ((u >> 16) & 1u);   // round-to-nearest-even
  return (unsigned short)(u >> 16);
}

__device__ __forceinline__ void load_lds16(const unsigned short* g, unsigned short* l) {
  __builtin_amdgcn_global_load_lds(
      (const __attribute__((address_space(1))) void*)g,
      (__attribute__((address_space(3))) void*)l, 16, 0, 0);
}

__device__ __forceinline__ uint32_t cvtpk_bf16(float lo, float hi) {
  uint32_t d;
  asm("v_cvt_pk_bf16_f32 %0, %1, %2" : "=v"(d) : "v"(lo), "v"(hi));
  return d;
}

// ---------------- fast zero (rocclr fill is erratic for 8 MB) ----------------
__global__ __launch_bounds__(256) void zero_kernel(float4* __restrict__ p) {
  p[(size_t)blockIdx.x * 256 + threadIdx.x] = make_float4(0.f, 0.f, 0.f, 0.f);
}

// ---------------- router: logits, softmax, argmax; NO global atomics ----------------
__global__ __launch_bounds__(256) void router_kernel(
    const float* __restrict__ x, const float* __restrict__ sw,
    const float* __restrict__ sb, float* __restrict__ pmax_out,
    int* __restrict__ routes, float* __restrict__ probs,
    unsigned short* __restrict__ xbf) {
  const int wave = threadIdx.x >> 6, lane = threadIdx.x & 63;
  const int t = blockIdx.x * 4 + wave;
  const float* xr = x + (size_t)t * D_DIM;
  float acc[8];
#pragma unroll
  for (int e = 0; e < 8; ++e) acc[e] = 0.f;
#pragma unroll
  for (int i = 0; i < 4; ++i) {
    const int d = i * 256 + lane * 4;
    float4 xv = *(const float4*)(xr + d);
    ushort4 h;
    h.x = f2bf(xv.x); h.y = f2bf(xv.y); h.z = f2bf(xv.z); h.w = f2bf(xv.w);
    *(ushort4*)(xbf + (size_t)t * D_DIM + d) = h;
    const float xs[4] = {xv.x, xv.y, xv.z, xv.w};
#pragma unroll
    for (int j = 0; j < 4; ++j) {
      const float4* swp = (const float4*)(sw + (size_t)(d + j) * 8);
      float4 w0 = swp[0], w1 = swp[1];
      acc[0] += xs[j] * w0.x; acc[1] += xs[j] * w0.y;
      acc[2] += xs[j] * w0.z; acc[3] += xs[j] * w0.w;
      acc[4] += xs[j] * w1.x; acc[5] += xs[j] * w1.y;
      acc[6] += xs[j] * w1.z; acc[7] += xs[j] * w1.w;
    }
  }
#pragma unroll
  for (int e = 0; e < 8; ++e) {
    float v = acc[e];
    for (int o = 32; o > 0; o >>= 1) v += __shfl_down(v, o, 64);
    acc[e] = v;
  }
  if (lane == 0) {
#pragma unroll
    for (int e = 0; e < 8; ++e) acc[e] += sb[e];
    int am = 0; float mx = acc[0];
#pragma unroll
    for (int e = 1; e < 8; ++e) if (acc[e] > mx) { mx = acc[e]; am = e; }  // first-max wins
    float p[8]; float s = 0.f;
#pragma unroll
    for (int e = 0; e < 8; ++e) { p[e] = expf(acc[e] - mx); s += p[e]; }
    float inv = 1.0f / s;
    pmax_out[t] = inv;
    routes[t] = am;
#pragma unroll
    for (int e = 0; e < 8; ++e) probs[(size_t)t * 8 + e] = p[e] * inv;
  }
}

// -------- plan: counts/psums reduce, 256-aligned offsets, perm init, scatter --------
__global__ __launch_bounds__(256) void plan_kernel(
    const int* __restrict__ routes, const float* __restrict__ probs,
    int* __restrict__ off, int* __restrict__ perm_out, int* __restrict__ perm_src,
    float* __restrict__ out_counts, float* __restrict__ out_psums,
    float* __restrict__ out_zero) {
  __shared__ int cnt[8];
  __shared__ int cur[8];
  __shared__ int offs[9];
  __shared__ float red[256][8];
  const int tid = threadIdx.x;
  if (tid < 8) cnt[tid] = 0;
  for (int i = tid; i < RPMAX; i += 256) { perm_out[i] = -1; perm_src[i] = 0; }
  __syncthreads();
  float loc[8];
#pragma unroll
  for (int e = 0; e < 8; ++e) loc[e] = 0.f;
  for (int t = tid; t < T_TOK; t += 256) {
    atomicAdd(&cnt[routes[t]], 1);
    const float4* p = (const float4*)(probs + (size_t)t * 8);
    float4 a = p[0], b = p[1];
    loc[0] += a.x; loc[1] += a.y; loc[2] += a.z; loc[3] += a.w;
    loc[4] += b.x; loc[5] += b.y; loc[6] += b.z; loc[7] += b.w;
  }
#pragma unroll
  for (int e = 0; e < 8; ++e) red[tid][e] = loc[e];
  __syncthreads();
  for (int s = 128; s >= 1; s >>= 1) {
    if (tid < s) {
#pragma unroll
      for (int e = 0; e < 8; ++e) red[tid][e] += red[tid + s][e];
    }
    __syncthreads();
  }
  if (tid == 0) {
    int o = 0;
    for (int e = 0; e < 8; ++e) { offs[e] = o; o += ((cnt[e] + 255) >> 8) << 8; }
    offs[8] = o;
    *out_zero = 0.0f;
  }
  __syncthreads();
  if (tid < 9) off[tid] = offs[tid];
  if (tid < 8) {
    cur[tid] = offs[tid];
    out_counts[tid] = (float)cnt[tid];
    out_psums[tid] = red[0][tid];
  }
  __syncthreads();
  for (int t = tid; t < T_TOK; t += 256) {
    int e = routes[t];
    int pos = atomicAdd(&cur[e], 1);
    perm_out[pos] = t;
    perm_src[pos] = t;
  }
}

// ---------------- gather: xg[slot] = xbf[perm_src[slot]] (contiguous A for GEMM1) ----
__global__ __launch_bounds__(256) void gather_kernel(
    const unsigned short* __restrict__ xbf, const int* __restrict__ off,
    const int* __restrict__ perm_src, unsigned short* __restrict__ xg) {
  const int wave = threadIdx.x >> 6, lane = threadIdx.x & 63;
  const int row = blockIdx.x * 4 + wave;
  if (row >= off[8]) return;
  const int tok = perm_src[row];              // pads -> token 0 (garbage rows, skipped at output)
  const bfx8* s = (const bfx8*)(xbf + (size_t)tok * D_DIM);
  bfx8* d = (bfx8*)(xg + (size_t)row * D_DIM);
  d[lane] = s[lane];
  d[lane + 64] = s[lane + 64];
}

// ---------------- fused grouped GEMM, 256x256 tile, 8 waves, 2-phase ----------------
// BM=256 x BN=256 tile, BK=64, 8 waves (2m x 4n), wave out 128x64. LDS 128KB dbuf.
// A (bf16, contiguous rows) via global_load_lds (pre-swizzled src, key row&7);
// B: fp32 W -> float4 reg load (t+1, issued BEFORE compute t) -> cvt_pk bf16 ->
// reg transpose -> swizzled ds_write_b64 AFTER compute. 64 MFMA/wave/step (~620cy
// per SIMD at 2 waves/SIMD) covers B-load latency; __syncthreads-only sync.
// KSPLIT>1: split-K over bz, atomicAdd epilogue into zeroed Out.
template <int BN, int K_, int N_, int KSPLIT, bool FIRST>
__global__ __launch_bounds__(512, 2) void gemm256(
    const unsigned short* __restrict__ A,    // FIRST: xg [RP][K_]; else H [RP][K_]
    const float* __restrict__ W,             // [E][K_][N_] fp32
    const float* __restrict__ Bias,          // [E][N_]
    const int* __restrict__ off,
    const int* __restrict__ perm_out,
    const float* __restrict__ pmax,
    unsigned short* __restrict__ Hout, float* __restrict__ Out) {
  constexpr int BM = 256;
  constexpr int KS = K_ / KSPLIT;
  constexpr int NT = KS / BK;
  constexpr int FM = 8;              // 128/16 rows per wave
  constexpr int FN = BN / 64;        // 4; wave-N = 64
  constexpr int GRP = BN / 128;      // 2
  constexpr int NBX = N_ / BN;
  __shared__ __align__(16) unsigned short As[2][BM * 64];
  __shared__ __align__(16) unsigned short Bs[2][BN * 64];
  const int tid = threadIdx.x;
  const int nby = gridDim.y;
  // XCD swizzle, n-chunked: XCD = dispatch-linear & 7
  const int lin = (blockIdx.z * nby + blockIdx.y) * NBX + blockIdx.x;
  const int total = NBX * nby * KSPLIT;
  const int newlin = (lin & 7) * (total >> 3) + (lin >> 3);
  const int bx = newlin / (nby * KSPLIT);
  const int rem = newlin % (nby * KSPLIT);
  const int by = rem % nby;
  const int kz = rem / nby;
  const int rowbase = by * BM;
  if (rowbase >= off[8]) return;
  int e = 0;
#pragma unroll
  for (int i = 1; i <= 7; ++i) if (rowbase >= off[i]) e = i;
  const int n0 = bx * BN;
  const int k0base = kz * KS;
  const int wave = tid >> 6, lane = tid & 63;
  const int wm = wave >> 2, wn = wave & 3;
  const float* Wn0 = W + (size_t)e * K_ * N_ + n0;

  // A: per-lane pre-swizzled global sources (m173): LDS linear, src chunk XOR'd
  const unsigned short* aSrc[4];
#pragma unroll
  for (int c = 0; c < 4; ++c) {
    int ca = (wave * 4 + c) * 64 + lane;      // 16B-chunk id, 0..2047
    int row = ca >> 3, slot = ca & 7;
    int sc = slot ^ (row & 7);
    aSrc[c] = A + (size_t)(rowbase + row) * K_ + k0base + sc * 8;
  }

  const int nq = lane & 15;                  // col quad within 64-col block
  const int qg = lane >> 4;                  // 0..3: (k-quad, col-block) selector
  const int kq = (qg & 1) * 4;               // k-quad offset within wave's 8 k-rows
  fx4 br[GRP][4];                            // B staging regs (reloaded every iter)

  auto A_STAGE = [&](int kt, unsigned short* Asb) {
#pragma unroll
    for (int c = 0; c < 4; ++c)
      load_lds16(aSrc[c] + kt, Asb + (wave * 4 + c) * 512);
  };
  auto B_LOAD = [&](int kt) {
#pragma unroll
    for (int g = 0; g < GRP; ++g) {
      const int cb = g * 2 + (qg >> 1);
#pragma unroll
      for (int j = 0; j < 4; ++j)
        br[g][j] = *(const fx4*)(Wn0 + (size_t)(kt + wave * 8 + kq + j) * N_ +
                                 cb * 64 + nq * 4);
    }
  };
  auto B_STORE = [&](unsigned short* Bsb) {
#pragma unroll
    for (int g = 0; g < GRP; ++g) {
      const int cb = g * 2 + (qg >> 1);
#pragma unroll
      for (int i = 0; i < 4; ++i) {
        const int nl = cb * 64 + nq * 4 + i;
        const int key = ((nl >> 2) + 2 * (nl & 3)) & 7;
        uint32_t d0 = cvtpk_bf16(br[g][0][i], br[g][1][i]);
        uint32_t d1 = cvtpk_bf16(br[g][2][i], br[g][3][i]);
        *(uint2*)(Bsb + nl * 64 + (wave ^ key) * 8 + kq) = make_uint2(d0, d1);
      }
    }
  };

  fx4 acc[FM][FN];
#pragma unroll
  for (int a = 0; a < FM; ++a)
#pragma unroll
    for (int b = 0; b < FN; ++b) acc[a][b] = (fx4){0.f, 0.f, 0.f, 0.f};

  auto COMPUTE = [&](const unsigned short* Asb, const unsigned short* Bsb) {
#pragma unroll
    for (int kk = 0; kk < 2; ++kk) {
      bfx8 af[FM], bf[FN];
#pragma unroll
      for (int fm = 0; fm < FM; ++fm) {
        int r = wm * 128 + fm * 16 + (lane & 15);
        int c = (kk * 4 + (lane >> 4)) ^ (r & 7);
        af[fm] = *(const bfx8*)(Asb + r * 64 + c * 8);
      }
#pragma unroll
      for (int fn = 0; fn < FN; ++fn) {
        int nn = wn * (BN / 4) + fn * 16 + (lane & 15);
        int key = ((nn >> 2) + 2 * (nn & 3)) & 7;
        int c = (kk * 4 + (lane >> 4)) ^ key;
        bf[fn] = *(const bfx8*)(Bsb + nn * 64 + c * 8);
      }
#pragma unroll
      for (int fm = 0; fm < FM; ++fm)
#pragma unroll
        for (int fn = 0; fn < FN; ++fn)
          acc[fm][fn] = __builtin_amdgcn_mfma_f32_16x16x32_bf16(
              af[fm], bf[fn], acc[fm][fn], 0, 0, 0);
    }
  };

  // ---- prologue: tile 0 into buf 0 ----
  A_STAGE(0, As[0]);
  B_LOAD(0);
  B_STORE(Bs[0]);
  __syncthreads();

  // ---- main loop: 2-phase double-buffered ----
  for (int t = 0; t < NT; ++t) {
    const int c = t & 1;
    if (t + 1 < NT) {
      A_STAGE((t + 1) * BK, As[c ^ 1]);   // DMA, covered by COMPUTE below
      B_LOAD((t + 1) * BK);               // reg loads, covered by COMPUTE
    }
    COMPUTE(As[c], Bs[c]);                // 64 MFMA/wave
    if (t + 1 < NT) B_STORE(Bs[c ^ 1]);   // cvt+ds_write after compute
    __syncthreads();
  }

  // ---- epilogue ----
  const int colbase = n0 + wn * (BN / 4);
  if (FIRST) {
#pragma unroll
    for (int fn = 0; fn < FN; ++fn) {
      int colg = colbase + fn * 16 + (lane & 15);
      float bv = Bias[(size_t)e * N_ + colg];
#pragma unroll
      for (int fm = 0; fm < FM; ++fm) {
        int rg = rowbase + wm * 128 + fm * 16 + ((lane >> 4) << 2);
#pragma unroll
        for (int j = 0; j < 4; ++j) {
          float v = fmaxf(acc[fm][fn][j] + bv, 0.f);
          Hout[(size_t)(rg + j) * N_ + colg] = f2bf(v);
        }
      }
    }
  } else {
#pragma unroll
    for (int fm = 0; fm < FM; ++fm) {
      int rg = rowbase + wm * 128 + fm * 16 + ((lane >> 4) << 2);
#pragma unroll
      for (int j = 0; j < 4; ++j) {
        int tok = perm_out[rg + j];
        if (tok < 0) continue;
        float pm = pmax[tok];
#pragma unroll
        for (int fn = 0; fn < FN; ++fn) {
          int colg = colbase + fn * 16 + (lane & 15);
          float v = acc[fm][fn][j];
          if (kz == 0) v += Bias[(size_t)e * N_ + colg];
          atomicAdd(&Out[(size_t)tok * N_ + colg], v * pm);
        }
      }
    }
  }
}

extern "C" void kernel_launch(void* const* d_in, const int* in_sizes, int n_in,
                              void* d_out, int out_size, void* d_ws, size_t ws_size,
                              hipStream_t stream) {
  const float* x  = (const float*)d_in[0];
  const float* sw = (const float*)d_in[1];
  const float* sb = (const float*)d_in[2];
  const float* w1 = (const float*)d_in[3];
  const float* b1 = (const float*)d_in[4];
  const float* w2 = (const float*)d_in[5];
  const float* b2 = (const float*)d_in[6];
  float* out = (float*)d_out;

  char* ws = (char*)d_ws;
  int*   off      = (int*)(ws + 0);          // 9 ints
  int*   routes   = (int*)(ws + 1024);       // 2048 ints
  int*   perm_out = (int*)(ws + 16384);      // RPMAX ints (pads -1)
  int*   perm_src = (int*)(ws + 32768);      // RPMAX ints (pads 0)
  float* probs    = (float*)(ws + 65536);    // 2048x8 fp32
  unsigned short* xbf = (unsigned short*)(ws + (1u << 20));   // 4 MB
  unsigned short* H   = (unsigned short*)(ws + (8u << 20));   // RPMAX x 4096 bf16 = 32 MB
  unsigned short* xg  = (unsigned short*)(ws + (40u << 20));  // RPMAX x 1024 bf16 = 8 MB

  // d_out layout: final(2097152) | counts(8) | psums(8) | 0(1) | pmax(2048)
  float* out_final  = out;
  float* out_counts = out + 2097152;
  float* out_psums  = out + 2097160;
  float* out_zero   = out + 2097168;
  float* out_pmax   = out + 2097169;

  // split-K GEMM2 accumulates atomically into out_final -> zero it (custom kernel)
  zero_kernel<<<2048, 256, 0, stream>>>((float4*)out_final);

  router_kernel<<<T_TOK / 4, 256, 0, stream>>>(x, sw, sb, out_pmax, routes, probs, xbf);
  plan_kernel<<<1, 256, 0, stream>>>(routes, probs, off, perm_out, perm_src,
                                     out_counts, out_psums, out_zero);
  gather_kernel<<<RPMAX / 4, 256, 0, stream>>>(xbf, off, perm_src, xg);

  // GEMM1: xg[RP,1024] x W1 -> H (relu, bf16). 256x256 tile, grid 16x16=256.
  gemm256<256, D_DIM, F_DIM, 1, true>
      <<<dim3(F_DIM / 256, RPMAX / 256, 1), 512, 0, stream>>>(
          xg, w1, b1, off, perm_out, nullptr, H, nullptr);
  // GEMM2: H[RP,4096] x W2 -> out (bias, *pmax, scatter, atomic split-K=4).
  // 256x256 tile (same per-step shape as GEMM1: NT=16, 64 MFMA/wave/step),
  // grid 4x16x4=256 blocks, n-chunked.
  gemm256<256, F_DIM, D_DIM, 4, false>
      <<<dim3(D_DIM / 256, RPMAX / 256, 4), 512, 0, stream>>>(
          H, w2, b2, off, perm_out, out_pmax, nullptr, out_final);
}

// Round 17
// 135.775 us; speedup vs baseline: 1.3734x; 1.3734x over previous
//
#include <hip/hip_runtime.h>
#include <stdint.h>

// Problem constants (B=2,S=1024,D=1024,F=4096,E=8)
#define T_TOK 2048
#define D_DIM 1024
#define F_DIM 4096
#define E_NUM 8
#define RPMAX 4096   // max padded rows at 256-alignment: 2048 + 8*255 -> 4096
#define BK 64

typedef __attribute__((ext_vector_type(8))) short bfx8;   // 8 bf16 (4 VGPR)
typedef __attribute__((ext_vector_type(4))) float fx4;    // MFMA accum / staging

__device__ __forceinline__ unsigned short f2bf(float f) {
  union { float f; uint32_t u; } v; v.f = f;
  uint32_t u = v.u;
  u += 0x7FFFu + ((u >> 16) & 1u);   // round-to-nearest-even
  return (unsigned short)(u >> 16);
}

__device__ __forceinline__ void load_lds16(const unsigned short* g, unsigned short* l) {
  __builtin_amdgcn_global_load_lds(
      (const __attribute__((address_space(1))) void*)g,
      (__attribute__((address_space(3))) void*)l, 16, 0, 0);
}

__device__ __forceinline__ uint32_t cvtpk_bf16(float lo, float hi) {
  uint32_t d;
  asm("v_cvt_pk_bf16_f32 %0, %1, %2" : "=v"(d) : "v"(lo), "v"(hi));
  return d;
}

// ---------------- router: logits, softmax, argmax; NO global atomics ----------------
__global__ __launch_bounds__(256) void router_kernel(
    const float* __restrict__ x, const float* __restrict__ sw,
    const float* __restrict__ sb, float* __restrict__ pmax_out,
    int* __restrict__ routes, float* __restrict__ probs,
    unsigned short* __restrict__ xbf) {
  const int wave = threadIdx.x >> 6, lane = threadIdx.x & 63;
  const int t = blockIdx.x * 4 + wave;
  const float* xr = x + (size_t)t * D_DIM;
  float acc[8];
#pragma unroll
  for (int e = 0; e < 8; ++e) acc[e] = 0.f;
#pragma unroll
  for (int i = 0; i < 4; ++i) {
    const int d = i * 256 + lane * 4;
    float4 xv = *(const float4*)(xr + d);
    ushort4 h;
    h.x = f2bf(xv.x); h.y = f2bf(xv.y); h.z = f2bf(xv.z); h.w = f2bf(xv.w);
    *(ushort4*)(xbf + (size_t)t * D_DIM + d) = h;
    const float xs[4] = {xv.x, xv.y, xv.z, xv.w};
#pragma unroll
    for (int j = 0; j < 4; ++j) {
      const float4* swp = (const float4*)(sw + (size_t)(d + j) * 8);
      float4 w0 = swp[0], w1 = swp[1];
      acc[0] += xs[j] * w0.x; acc[1] += xs[j] * w0.y;
      acc[2] += xs[j] * w0.z; acc[3] += xs[j] * w0.w;
      acc[4] += xs[j] * w1.x; acc[5] += xs[j] * w1.y;
      acc[6] += xs[j] * w1.z; acc[7] += xs[j] * w1.w;
    }
  }
#pragma unroll
  for (int e = 0; e < 8; ++e) {
    float v = acc[e];
    for (int o = 32; o > 0; o >>= 1) v += __shfl_down(v, o, 64);
    acc[e] = v;
  }
  if (lane == 0) {
#pragma unroll
    for (int e = 0; e < 8; ++e) acc[e] += sb[e];
    int am = 0; float mx = acc[0];
#pragma unroll
    for (int e = 1; e < 8; ++e) if (acc[e] > mx) { mx = acc[e]; am = e; }  // first-max wins
    float p[8]; float s = 0.f;
#pragma unroll
    for (int e = 0; e < 8; ++e) { p[e] = expf(acc[e] - mx); s += p[e]; }
    float inv = 1.0f / s;
    pmax_out[t] = inv;
    routes[t] = am;
#pragma unroll
    for (int e = 0; e < 8; ++e) probs[(size_t)t * 8 + e] = p[e] * inv;
  }
}

// -------- plan: counts/psums reduce, 256-aligned offsets, perm init, scatter --------
__global__ __launch_bounds__(256) void plan_kernel(
    const int* __restrict__ routes, const float* __restrict__ probs,
    int* __restrict__ off, int* __restrict__ perm_out, int* __restrict__ perm_src,
    float* __restrict__ out_counts, float* __restrict__ out_psums,
    float* __restrict__ out_zero) {
  __shared__ int cnt[8];
  __shared__ int cur[8];
  __shared__ int offs[9];
  __shared__ float red[256][8];
  const int tid = threadIdx.x;
  if (tid < 8) cnt[tid] = 0;
  for (int i = tid; i < RPMAX; i += 256) { perm_out[i] = -1; perm_src[i] = 0; }
  __syncthreads();
  float loc[8];
#pragma unroll
  for (int e = 0; e < 8; ++e) loc[e] = 0.f;
  for (int t = tid; t < T_TOK; t += 256) {
    atomicAdd(&cnt[routes[t]], 1);
    const float4* p = (const float4*)(probs + (size_t)t * 8);
    float4 a = p[0], b = p[1];
    loc[0] += a.x; loc[1] += a.y; loc[2] += a.z; loc[3] += a.w;
    loc[4] += b.x; loc[5] += b.y; loc[6] += b.z; loc[7] += b.w;
  }
#pragma unroll
  for (int e = 0; e < 8; ++e) red[tid][e] = loc[e];
  __syncthreads();
  for (int s = 128; s >= 1; s >>= 1) {
    if (tid < s) {
#pragma unroll
      for (int e = 0; e < 8; ++e) red[tid][e] += red[tid + s][e];
    }
    __syncthreads();
  }
  if (tid == 0) {
    int o = 0;
    for (int e = 0; e < 8; ++e) { offs[e] = o; o += ((cnt[e] + 255) >> 8) << 8; }
    offs[8] = o;
    *out_zero = 0.0f;
  }
  __syncthreads();
  if (tid < 9) off[tid] = offs[tid];
  if (tid < 8) {
    cur[tid] = offs[tid];
    out_counts[tid] = (float)cnt[tid];
    out_psums[tid] = red[0][tid];
  }
  __syncthreads();
  for (int t = tid; t < T_TOK; t += 256) {
    int e = routes[t];
    int pos = atomicAdd(&cur[e], 1);
    perm_out[pos] = t;
    perm_src[pos] = t;
  }
}

// ---------------- gather: xg[slot] = xbf[perm_src[slot]] (contiguous A for GEMM1) ----
__global__ __launch_bounds__(256) void gather_kernel(
    const unsigned short* __restrict__ xbf, const int* __restrict__ off,
    const int* __restrict__ perm_src, unsigned short* __restrict__ xg) {
  const int wave = threadIdx.x >> 6, lane = threadIdx.x & 63;
  const int row = blockIdx.x * 4 + wave;
  if (row >= off[8]) return;
  const int tok = perm_src[row];              // pads -> token 0 (garbage rows, skipped at output)
  const bfx8* s = (const bfx8*)(xbf + (size_t)tok * D_DIM);
  bfx8* d = (bfx8*)(xg + (size_t)row * D_DIM);
  d[lane] = s[lane];
  d[lane + 64] = s[lane + 64];
}

// ---------------- reduce: out[tok] = (sum_kz P[kz][row] + b2[e]) * pmax[tok] ----------
// Coalesced: replaces GEMM2's scattered-atomic epilogue (R16's ~75 us cost).
__global__ __launch_bounds__(256) void reduce_kernel(
    const float* __restrict__ P, const int* __restrict__ off,
    const int* __restrict__ perm_out, const float* __restrict__ b2,
    const float* __restrict__ pmax, float* __restrict__ out) {
  const int row = blockIdx.x;
  if (row >= off[8]) return;
  const int tok = perm_out[row];
  if (tok < 0) return;
  int e = 0;
#pragma unroll
  for (int i = 1; i <= 7; ++i) if (row >= off[i]) e = i;
  const int col = threadIdx.x * 4;
  const size_t base = (size_t)row * D_DIM + col;
  float4 p0 = *(const float4*)(P + base);
  float4 p1 = *(const float4*)(P + (size_t)1 * RPMAX * D_DIM + base);
  float4 p2 = *(const float4*)(P + (size_t)2 * RPMAX * D_DIM + base);
  float4 p3 = *(const float4*)(P + (size_t)3 * RPMAX * D_DIM + base);
  float4 bv = *(const float4*)(b2 + (size_t)e * D_DIM + col);
  const float pm = pmax[tok];
  float4 r;
  r.x = (p0.x + p1.x + p2.x + p3.x + bv.x) * pm;
  r.y = (p0.y + p1.y + p2.y + p3.y + bv.y) * pm;
  r.z = (p0.z + p1.z + p2.z + p3.z + bv.z) * pm;
  r.w = (p0.w + p1.w + p2.w + p3.w + bv.w) * pm;
  *(float4*)(out + (size_t)tok * D_DIM + col) = r;
}

// ---------------- fused grouped GEMM, 256x256 tile, 8 waves, 2-phase ----------------
// BM=256 x BN=256 tile, BK=64, 8 waves (2m x 4n), wave out 128x64. LDS 128KB dbuf.
// A (bf16, contiguous rows) via global_load_lds (pre-swizzled src, key row&7);
// B: fp32 W -> float4 reg load (t+1, issued BEFORE compute t) -> cvt_pk bf16 ->
// reg transpose -> swizzled ds_write_b64 AFTER compute. 64 MFMA/wave/step covers
// B-load latency; __syncthreads-only sync.
// FIRST: H = relu(A@W1+b1) bf16. else: coalesced fp32 partials P[kz][row][col]
// (NO scattered atomics -- reduce_kernel finishes).
template <int BN, int K_, int N_, int KSPLIT, bool FIRST>
__global__ __launch_bounds__(512, 2) void gemm256(
    const unsigned short* __restrict__ A,    // FIRST: xg [RP][K_]; else H [RP][K_]
    const float* __restrict__ W,             // [E][K_][N_] fp32
    const float* __restrict__ Bias,          // [E][N_]
    const int* __restrict__ off,
    unsigned short* __restrict__ Hout, float* __restrict__ Pout) {
  constexpr int BM = 256;
  constexpr int KS = K_ / KSPLIT;
  constexpr int NT = KS / BK;
  constexpr int FM = 8;              // 128/16 rows per wave
  constexpr int FN = BN / 64;        // 4; wave-N = 64
  constexpr int GRP = BN / 128;      // 2
  constexpr int NBX = N_ / BN;
  __shared__ __align__(16) unsigned short As[2][BM * 64];
  __shared__ __align__(16) unsigned short Bs[2][BN * 64];
  const int tid = threadIdx.x;
  const int nby = gridDim.y;
  // XCD swizzle, n-chunked: XCD = dispatch-linear & 7
  const int lin = (blockIdx.z * nby + blockIdx.y) * NBX + blockIdx.x;
  const int total = NBX * nby * KSPLIT;
  const int newlin = (lin & 7) * (total >> 3) + (lin >> 3);
  const int bx = newlin / (nby * KSPLIT);
  const int rem = newlin % (nby * KSPLIT);
  const int by = rem % nby;
  const int kz = rem / nby;
  const int rowbase = by * BM;
  if (rowbase >= off[8]) return;
  int e = 0;
#pragma unroll
  for (int i = 1; i <= 7; ++i) if (rowbase >= off[i]) e = i;
  const int n0 = bx * BN;
  const int k0base = kz * KS;
  const int wave = tid >> 6, lane = tid & 63;
  const int wm = wave >> 2, wn = wave & 3;
  const float* Wn0 = W + (size_t)e * K_ * N_ + n0;

  // A: per-lane pre-swizzled global sources (m173): LDS linear, src chunk XOR'd
  const unsigned short* aSrc[4];
#pragma unroll
  for (int c = 0; c < 4; ++c) {
    int ca = (wave * 4 + c) * 64 + lane;      // 16B-chunk id, 0..2047
    int row = ca >> 3, slot = ca & 7;
    int sc = slot ^ (row & 7);
    aSrc[c] = A + (size_t)(rowbase + row) * K_ + k0base + sc * 8;
  }

  const int nq = lane & 15;                  // col quad within 64-col block
  const int qg = lane >> 4;                  // 0..3: (k-quad, col-block) selector
  const int kq = (qg & 1) * 4;               // k-quad offset within wave's 8 k-rows
  fx4 br[GRP][4];                            // B staging regs (reloaded every iter)

  auto A_STAGE = [&](int kt, unsigned short* Asb) {
#pragma unroll
    for (int c = 0; c < 4; ++c)
      load_lds16(aSrc[c] + kt, Asb + (wave * 4 + c) * 512);
  };
  auto B_LOAD = [&](int kt) {
#pragma unroll
    for (int g = 0; g < GRP; ++g) {
      const int cb = g * 2 + (qg >> 1);
#pragma unroll
      for (int j = 0; j < 4; ++j)
        br[g][j] = *(const fx4*)(Wn0 + (size_t)(kt + wave * 8 + kq + j) * N_ +
                                 cb * 64 + nq * 4);
    }
  };
  auto B_STORE = [&](unsigned short* Bsb) {
#pragma unroll
    for (int g = 0; g < GRP; ++g) {
      const int cb = g * 2 + (qg >> 1);
#pragma unroll
      for (int i = 0; i < 4; ++i) {
        const int nl = cb * 64 + nq * 4 + i;
        const int key = ((nl >> 2) + 2 * (nl & 3)) & 7;
        uint32_t d0 = cvtpk_bf16(br[g][0][i], br[g][1][i]);
        uint32_t d1 = cvtpk_bf16(br[g][2][i], br[g][3][i]);
        *(uint2*)(Bsb + nl * 64 + (wave ^ key) * 8 + kq) = make_uint2(d0, d1);
      }
    }
  };

  fx4 acc[FM][FN];
#pragma unroll
  for (int a = 0; a < FM; ++a)
#pragma unroll
    for (int b = 0; b < FN; ++b) acc[a][b] = (fx4){0.f, 0.f, 0.f, 0.f};

  auto COMPUTE = [&](const unsigned short* Asb, const unsigned short* Bsb) {
#pragma unroll
    for (int kk = 0; kk < 2; ++kk) {
      bfx8 af[FM], bf[FN];
#pragma unroll
      for (int fm = 0; fm < FM; ++fm) {
        int r = wm * 128 + fm * 16 + (lane & 15);
        int c = (kk * 4 + (lane >> 4)) ^ (r & 7);
        af[fm] = *(const bfx8*)(Asb + r * 64 + c * 8);
      }
#pragma unroll
      for (int fn = 0; fn < FN; ++fn) {
        int nn = wn * (BN / 4) + fn * 16 + (lane & 15);
        int key = ((nn >> 2) + 2 * (nn & 3)) & 7;
        int c = (kk * 4 + (lane >> 4)) ^ key;
        bf[fn] = *(const bfx8*)(Bsb + nn * 64 + c * 8);
      }
#pragma unroll
      for (int fm = 0; fm < FM; ++fm)
#pragma unroll
        for (int fn = 0; fn < FN; ++fn)
          acc[fm][fn] = __builtin_amdgcn_mfma_f32_16x16x32_bf16(
              af[fm], bf[fn], acc[fm][fn], 0, 0, 0);
    }
  };

  // ---- prologue: tile 0 into buf 0 ----
  A_STAGE(0, As[0]);
  B_LOAD(0);
  B_STORE(Bs[0]);
  __syncthreads();

  // ---- main loop: 2-phase double-buffered ----
  for (int t = 0; t < NT; ++t) {
    const int c = t & 1;
    if (t + 1 < NT) {
      A_STAGE((t + 1) * BK, As[c ^ 1]);   // DMA, covered by COMPUTE below
      B_LOAD((t + 1) * BK);               // reg loads, covered by COMPUTE
    }
    COMPUTE(As[c], Bs[c]);                // 64 MFMA/wave
    if (t + 1 < NT) B_STORE(Bs[c ^ 1]);   // cvt+ds_write after compute
    __syncthreads();
  }

  // ---- epilogue ----
  const int colbase = n0 + wn * (BN / 4);
  if (FIRST) {
#pragma unroll
    for (int fn = 0; fn < FN; ++fn) {
      int colg = colbase + fn * 16 + (lane & 15);
      float bv = Bias[(size_t)e * N_ + colg];
#pragma unroll
      for (int fm = 0; fm < FM; ++fm) {
        int rg = rowbase + wm * 128 + fm * 16 + ((lane >> 4) << 2);
#pragma unroll
        for (int j = 0; j < 4; ++j) {
          float v = fmaxf(acc[fm][fn][j] + bv, 0.f);
          Hout[(size_t)(rg + j) * N_ + colg] = f2bf(v);
        }
      }
    }
  } else {
    // coalesced fp32 partial store: P[kz][row][col] (no atomics, no scatter)
    float* Pk = Pout + (size_t)kz * RPMAX * N_;
#pragma unroll
    for (int fm = 0; fm < FM; ++fm) {
      int rg = rowbase + wm * 128 + fm * 16 + ((lane >> 4) << 2);
#pragma unroll
      for (int j = 0; j < 4; ++j) {
#pragma unroll
        for (int fn = 0; fn < FN; ++fn) {
          int colg = colbase + fn * 16 + (lane & 15);
          Pk[(size_t)(rg + j) * N_ + colg] = acc[fm][fn][j];
        }
      }
    }
  }
}

extern "C" void kernel_launch(void* const* d_in, const int* in_sizes, int n_in,
                              void* d_out, int out_size, void* d_ws, size_t ws_size,
                              hipStream_t stream) {
  const float* x  = (const float*)d_in[0];
  const float* sw = (const float*)d_in[1];
  const float* sb = (const float*)d_in[2];
  const float* w1 = (const float*)d_in[3];
  const float* b1 = (const float*)d_in[4];
  const float* w2 = (const float*)d_in[5];
  const float* b2 = (const float*)d_in[6];
  float* out = (float*)d_out;

  char* ws = (char*)d_ws;
  int*   off      = (int*)(ws + 0);          // 9 ints
  int*   routes   = (int*)(ws + 1024);       // 2048 ints
  int*   perm_out = (int*)(ws + 16384);      // RPMAX ints (pads -1)
  int*   perm_src = (int*)(ws + 32768);      // RPMAX ints (pads 0)
  float* probs    = (float*)(ws + 65536);    // 2048x8 fp32
  unsigned short* xbf = (unsigned short*)(ws + (1u << 20));   // 4 MB
  unsigned short* H   = (unsigned short*)(ws + (8u << 20));   // RPMAX x 4096 bf16 = 32 MB
  unsigned short* xg  = (unsigned short*)(ws + (40u << 20));  // RPMAX x 1024 bf16 = 8 MB
  float* P            = (float*)(ws + (48u << 20));           // 4 x RPMAX x 1024 fp32 = 64 MB

  // d_out layout: final(2097152) | counts(8) | psums(8) | 0(1) | pmax(2048)
  float* out_final  = out;
  float* out_counts = out + 2097152;
  float* out_psums  = out + 2097160;
  float* out_zero   = out + 2097168;
  float* out_pmax   = out + 2097169;

  router_kernel<<<T_TOK / 4, 256, 0, stream>>>(x, sw, sb, out_pmax, routes, probs, xbf);
  plan_kernel<<<1, 256, 0, stream>>>(routes, probs, off, perm_out, perm_src,
                                     out_counts, out_psums, out_zero);
  gather_kernel<<<RPMAX / 4, 256, 0, stream>>>(xbf, off, perm_src, xg);

  // GEMM1: xg[RP,1024] x W1 -> H (relu, bf16). 256x256 tile, grid 16x16=256.
  gemm256<256, D_DIM, F_DIM, 1, true>
      <<<dim3(F_DIM / 256, RPMAX / 256, 1), 512, 0, stream>>>(
          xg, w1, b1, off, H, nullptr);
  // GEMM2: H[RP,4096] x W2 -> fp32 partials P[4][RP][1024] (coalesced stores).
  // 256x256 tile, split-K=4, grid 4x16x4=256 blocks, n-chunked.
  gemm256<256, F_DIM, D_DIM, 4, false>
      <<<dim3(D_DIM / 256, RPMAX / 256, 4), 512, 0, stream>>>(
          H, w2, b2, off, nullptr, P);
  // reduce: out[tok] = (sum_kz P + b2[e]) * pmax[tok], coalesced scatter.
  reduce_kernel<<<RPMAX, 256, 0, stream>>>(P, off, perm_out, b2, out_pmax, out_final);
}

// Round 18
// 132.667 us; speedup vs baseline: 1.4056x; 1.0234x over previous
//
#include <hip/hip_runtime.h>
#include <stdint.h>

// Problem constants (B=2,S=1024,D=1024,F=4096,E=8)
#define T_TOK 2048
#define D_DIM 1024
#define F_DIM 4096
#define E_NUM 8
#define RPMAX 4096   // max padded rows at 256-alignment
#define BK 64

typedef __attribute__((ext_vector_type(8))) short bfx8;   // 8 bf16 (4 VGPR)
typedef __attribute__((ext_vector_type(4))) float fx4;    // MFMA accum / staging

__device__ __forceinline__ unsigned short f2bf(float f) {
  union { float f; uint32_t u; } v; v.f = f;
  uint32_t u = v.u;
  u += 0x7FFFu + ((u >> 16) & 1u);   // round-to-nearest-even
  return (unsigned short)(u >> 16);
}

__device__ __forceinline__ void load_lds16(const unsigned short* g, unsigned short* l) {
  __builtin_amdgcn_global_load_lds(
      (const __attribute__((address_space(1))) void*)g,
      (__attribute__((address_space(3))) void*)l, 16, 0, 0);
}

__device__ __forceinline__ uint32_t cvtpk_bf16(float lo, float hi) {
  uint32_t d;
  asm("v_cvt_pk_bf16_f32 %0, %1, %2" : "=v"(d) : "v"(lo), "v"(hi));
  return d;
}

// ---------------- router: logits, softmax, argmax; NO global atomics ----------------
__global__ __launch_bounds__(256) void router_kernel(
    const float* __restrict__ x, const float* __restrict__ sw,
    const float* __restrict__ sb, float* __restrict__ pmax_out,
    int* __restrict__ routes, float* __restrict__ probs,
    unsigned short* __restrict__ xbf) {
  const int wave = threadIdx.x >> 6, lane = threadIdx.x & 63;
  const int t = blockIdx.x * 4 + wave;
  const float* xr = x + (size_t)t * D_DIM;
  float acc[8];
#pragma unroll
  for (int e = 0; e < 8; ++e) acc[e] = 0.f;
#pragma unroll
  for (int i = 0; i < 4; ++i) {
    const int d = i * 256 + lane * 4;
    float4 xv = *(const float4*)(xr + d);
    ushort4 h;
    h.x = f2bf(xv.x); h.y = f2bf(xv.y); h.z = f2bf(xv.z); h.w = f2bf(xv.w);
    *(ushort4*)(xbf + (size_t)t * D_DIM + d) = h;
    const float xs[4] = {xv.x, xv.y, xv.z, xv.w};
#pragma unroll
    for (int j = 0; j < 4; ++j) {
      const float4* swp = (const float4*)(sw + (size_t)(d + j) * 8);
      float4 w0 = swp[0], w1 = swp[1];
      acc[0] += xs[j] * w0.x; acc[1] += xs[j] * w0.y;
      acc[2] += xs[j] * w0.z; acc[3] += xs[j] * w0.w;
      acc[4] += xs[j] * w1.x; acc[5] += xs[j] * w1.y;
      acc[6] += xs[j] * w1.z; acc[7] += xs[j] * w1.w;
    }
  }
#pragma unroll
  for (int e = 0; e < 8; ++e) {
    float v = acc[e];
    for (int o = 32; o > 0; o >>= 1) v += __shfl_down(v, o, 64);
    acc[e] = v;
  }
  if (lane == 0) {
#pragma unroll
    for (int e = 0; e < 8; ++e) acc[e] += sb[e];
    int am = 0; float mx = acc[0];
#pragma unroll
    for (int e = 1; e < 8; ++e) if (acc[e] > mx) { mx = acc[e]; am = e; }  // first-max wins
    float p[8]; float s = 0.f;
#pragma unroll
    for (int e = 0; e < 8; ++e) { p[e] = expf(acc[e] - mx); s += p[e]; }
    float inv = 1.0f / s;
    pmax_out[t] = inv;
    routes[t] = am;
#pragma unroll
    for (int e = 0; e < 8; ++e) probs[(size_t)t * 8 + e] = p[e] * inv;
  }
}

// -------- plan: counts/psums reduce, 256-aligned offsets, perm init, scatter --------
__global__ __launch_bounds__(256) void plan_kernel(
    const int* __restrict__ routes, const float* __restrict__ probs,
    int* __restrict__ off, int* __restrict__ perm_out, int* __restrict__ perm_src,
    float* __restrict__ out_counts, float* __restrict__ out_psums,
    float* __restrict__ out_zero) {
  __shared__ int cnt[8];
  __shared__ int cur[8];
  __shared__ int offs[9];
  __shared__ float red[256][8];
  const int tid = threadIdx.x;
  if (tid < 8) cnt[tid] = 0;
  for (int i = tid; i < RPMAX; i += 256) { perm_out[i] = -1; perm_src[i] = 0; }
  __syncthreads();
  float loc[8];
#pragma unroll
  for (int e = 0; e < 8; ++e) loc[e] = 0.f;
  for (int t = tid; t < T_TOK; t += 256) {
    atomicAdd(&cnt[routes[t]], 1);
    const float4* p = (const float4*)(probs + (size_t)t * 8);
    float4 a = p[0], b = p[1];
    loc[0] += a.x; loc[1] += a.y; loc[2] += a.z; loc[3] += a.w;
    loc[4] += b.x; loc[5] += b.y; loc[6] += b.z; loc[7] += b.w;
  }
#pragma unroll
  for (int e = 0; e < 8; ++e) red[tid][e] = loc[e];
  __syncthreads();
  for (int s = 128; s >= 1; s >>= 1) {
    if (tid < s) {
#pragma unroll
      for (int e = 0; e < 8; ++e) red[tid][e] += red[tid + s][e];
    }
    __syncthreads();
  }
  if (tid == 0) {
    int o = 0;
    for (int e = 0; e < 8; ++e) { offs[e] = o; o += ((cnt[e] + 255) >> 8) << 8; }
    offs[8] = o;
    *out_zero = 0.0f;
  }
  __syncthreads();
  if (tid < 9) off[tid] = offs[tid];
  if (tid < 8) {
    cur[tid] = offs[tid];
    out_counts[tid] = (float)cnt[tid];
    out_psums[tid] = red[0][tid];
  }
  __syncthreads();
  for (int t = tid; t < T_TOK; t += 256) {
    int e = routes[t];
    int pos = atomicAdd(&cur[e], 1);
    perm_out[pos] = t;
    perm_src[pos] = t;
  }
}

// ---------------- gather: xg[slot] = xbf[perm_src[slot]] ----------------
__global__ __launch_bounds__(256) void gather_kernel(
    const unsigned short* __restrict__ xbf, const int* __restrict__ off,
    const int* __restrict__ perm_src, unsigned short* __restrict__ xg) {
  const int wave = threadIdx.x >> 6, lane = threadIdx.x & 63;
  const int row = blockIdx.x * 4 + wave;
  if (row >= off[8]) return;
  const int tok = perm_src[row];
  const bfx8* s = (const bfx8*)(xbf + (size_t)tok * D_DIM);
  bfx8* d = (bfx8*)(xg + (size_t)row * D_DIM);
  d[lane] = s[lane];
  d[lane + 64] = s[lane + 64];
}

// ---------------- reduce: out[tok] = (sum_kz P[kz][row] + b2[e]) * pmax[tok] ----------
__global__ __launch_bounds__(256) void reduce_kernel(
    const float* __restrict__ P, const int* __restrict__ off,
    const int* __restrict__ perm_out, const float* __restrict__ b2,
    const float* __restrict__ pmax, float* __restrict__ out) {
  const int row = blockIdx.x;
  if (row >= off[8]) return;
  const int tok = perm_out[row];
  if (tok < 0) return;
  int e = 0;
#pragma unroll
  for (int i = 1; i <= 7; ++i) if (row >= off[i]) e = i;
  const int col = threadIdx.x * 4;
  const size_t base = (size_t)row * D_DIM + col;
  float4 p0 = *(const float4*)(P + base);
  float4 p1 = *(const float4*)(P + (size_t)1 * RPMAX * D_DIM + base);
  float4 p2 = *(const float4*)(P + (size_t)2 * RPMAX * D_DIM + base);
  float4 p3 = *(const float4*)(P + (size_t)3 * RPMAX * D_DIM + base);
  float4 bv = *(const float4*)(b2 + (size_t)e * D_DIM + col);
  const float pm = pmax[tok];
  float4 r;
  r.x = (p0.x + p1.x + p2.x + p3.x + bv.x) * pm;
  r.y = (p0.y + p1.y + p2.y + p3.y + bv.y) * pm;
  r.z = (p0.z + p1.z + p2.z + p3.z + bv.z) * pm;
  r.w = (p0.w + p1.w + p2.w + p3.w + bv.w) * pm;
  *(float4*)(out + (size_t)tok * D_DIM + col) = r;
}

// ---------------- GEMM1: 256x256 tile, 8 waves, 2-phase (unchanged, at floor) --------
template <int BN, int K_, int N_, int KSPLIT, bool FIRST>
__global__ __launch_bounds__(512, 2) void gemm256(
    const unsigned short* __restrict__ A,
    const float* __restrict__ W, const float* __restrict__ Bias,
    const int* __restrict__ off,
    unsigned short* __restrict__ Hout, float* __restrict__ Pout) {
  constexpr int BM = 256;
  constexpr int KS = K_ / KSPLIT;
  constexpr int NT = KS / BK;
  constexpr int FM = 8;
  constexpr int FN = BN / 64;
  constexpr int GRP = BN / 128;
  constexpr int NBX = N_ / BN;
  __shared__ __align__(16) unsigned short As[2][BM * 64];
  __shared__ __align__(16) unsigned short Bs[2][BN * 64];
  const int tid = threadIdx.x;
  const int nby = gridDim.y;
  const int lin = (blockIdx.z * nby + blockIdx.y) * NBX + blockIdx.x;
  const int total = NBX * nby * KSPLIT;
  const int newlin = (lin & 7) * (total >> 3) + (lin >> 3);
  const int bx = newlin / (nby * KSPLIT);
  const int rem = newlin % (nby * KSPLIT);
  const int by = rem % nby;
  const int kz = rem / nby;
  const int rowbase = by * BM;
  if (rowbase >= off[8]) return;
  int e = 0;
#pragma unroll
  for (int i = 1; i <= 7; ++i) if (rowbase >= off[i]) e = i;
  const int n0 = bx * BN;
  const int k0base = kz * KS;
  const int wave = tid >> 6, lane = tid & 63;
  const int wm = wave >> 2, wn = wave & 3;
  const float* Wn0 = W + (size_t)e * K_ * N_ + n0;

  const unsigned short* aSrc[4];
#pragma unroll
  for (int c = 0; c < 4; ++c) {
    int ca = (wave * 4 + c) * 64 + lane;
    int row = ca >> 3, slot = ca & 7;
    int sc = slot ^ (row & 7);
    aSrc[c] = A + (size_t)(rowbase + row) * K_ + k0base + sc * 8;
  }

  const int nq = lane & 15;
  const int qg = lane >> 4;
  const int kq = (qg & 1) * 4;
  fx4 br[GRP][4];

  auto A_STAGE = [&](int kt, unsigned short* Asb) {
#pragma unroll
    for (int c = 0; c < 4; ++c)
      load_lds16(aSrc[c] + kt, Asb + (wave * 4 + c) * 512);
  };
  auto B_LOAD = [&](int kt) {
#pragma unroll
    for (int g = 0; g < GRP; ++g) {
      const int cb = g * 2 + (qg >> 1);
#pragma unroll
      for (int j = 0; j < 4; ++j)
        br[g][j] = *(const fx4*)(Wn0 + (size_t)(kt + wave * 8 + kq + j) * N_ +
                                 cb * 64 + nq * 4);
    }
  };
  auto B_STORE = [&](unsigned short* Bsb) {
#pragma unroll
    for (int g = 0; g < GRP; ++g) {
      const int cb = g * 2 + (qg >> 1);
#pragma unroll
      for (int i = 0; i < 4; ++i) {
        const int nl = cb * 64 + nq * 4 + i;
        const int key = ((nl >> 2) + 2 * (nl & 3)) & 7;
        uint32_t d0 = cvtpk_bf16(br[g][0][i], br[g][1][i]);
        uint32_t d1 = cvtpk_bf16(br[g][2][i], br[g][3][i]);
        *(uint2*)(Bsb + nl * 64 + (wave ^ key) * 8 + kq) = make_uint2(d0, d1);
      }
    }
  };

  fx4 acc[FM][FN];
#pragma unroll
  for (int a = 0; a < FM; ++a)
#pragma unroll
    for (int b = 0; b < FN; ++b) acc[a][b] = (fx4){0.f, 0.f, 0.f, 0.f};

  auto COMPUTE = [&](const unsigned short* Asb, const unsigned short* Bsb) {
#pragma unroll
    for (int kk = 0; kk < 2; ++kk) {
      bfx8 af[FM], bf[FN];
#pragma unroll
      for (int fm = 0; fm < FM; ++fm) {
        int r = wm * 128 + fm * 16 + (lane & 15);
        int c = (kk * 4 + (lane >> 4)) ^ (r & 7);
        af[fm] = *(const bfx8*)(Asb + r * 64 + c * 8);
      }
#pragma unroll
      for (int fn = 0; fn < FN; ++fn) {
        int nn = wn * (BN / 4) + fn * 16 + (lane & 15);
        int key = ((nn >> 2) + 2 * (nn & 3)) & 7;
        int c = (kk * 4 + (lane >> 4)) ^ key;
        bf[fn] = *(const bfx8*)(Bsb + nn * 64 + c * 8);
      }
#pragma unroll
      for (int fm = 0; fm < FM; ++fm)
#pragma unroll
        for (int fn = 0; fn < FN; ++fn)
          acc[fm][fn] = __builtin_amdgcn_mfma_f32_16x16x32_bf16(
              af[fm], bf[fn], acc[fm][fn], 0, 0, 0);
    }
  };

  A_STAGE(0, As[0]);
  B_LOAD(0);
  B_STORE(Bs[0]);
  __syncthreads();

  for (int t = 0; t < NT; ++t) {
    const int c = t & 1;
    if (t + 1 < NT) {
      A_STAGE((t + 1) * BK, As[c ^ 1]);
      B_LOAD((t + 1) * BK);
    }
    COMPUTE(As[c], Bs[c]);
    if (t + 1 < NT) B_STORE(Bs[c ^ 1]);
    __syncthreads();
  }

  const int colbase = n0 + wn * (BN / 4);
  if (FIRST) {
#pragma unroll
    for (int fn = 0; fn < FN; ++fn) {
      int colg = colbase + fn * 16 + (lane & 15);
      float bv = Bias[(size_t)e * N_ + colg];
#pragma unroll
      for (int fm = 0; fm < FM; ++fm) {
        int rg = rowbase + wm * 128 + fm * 16 + ((lane >> 4) << 2);
#pragma unroll
        for (int j = 0; j < 4; ++j) {
          float v = fmaxf(acc[fm][fn][j] + bv, 0.f);
          Hout[(size_t)(rg + j) * N_ + colg] = f2bf(v);
        }
      }
    }
  } else {
    float* Pk = Pout + (size_t)kz * RPMAX * N_;
#pragma unroll
    for (int fm = 0; fm < FM; ++fm) {
      int rg = rowbase + wm * 128 + fm * 16 + ((lane >> 4) << 2);
#pragma unroll
      for (int j = 0; j < 4; ++j) {
#pragma unroll
        for (int fn = 0; fn < FN; ++fn) {
          int colg = colbase + fn * 16 + (lane & 15);
          Pk[(size_t)(rg + j) * N_ + colg] = acc[fm][fn][j];
        }
      }
    }
  }
}

// ---------------- GEMM2: 128x256 tile, single-buffer, 48KB LDS, 2 blocks/CU ----------
// 8 waves (2m x 4n), wave out 64x64 (acc 64 VGPR). m97 loop: STAGE -> barrier ->
// COMPUTE -> barrier; exposed A-DMA/B-load latency covered by the co-resident
// sibling block's COMPUTE (m114 cross-block TLP). KSPLIT=4 over bz; coalesced
// fp32 partials P[kz]; reduce_kernel finishes.
template <int K_, int N_, int KSPLIT>
__global__ __launch_bounds__(512, 4) void gemm2s(
    const unsigned short* __restrict__ A,    // H [RP][K_]
    const float* __restrict__ W,             // [E][K_][N_] fp32
    const int* __restrict__ off,
    float* __restrict__ Pout) {
  constexpr int BM = 128, BN = 256;
  constexpr int KS = K_ / KSPLIT;
  constexpr int NT = KS / BK;
  constexpr int FM = 4, FN = 4, GRP = 2;
  constexpr int NBX = N_ / BN;
  __shared__ __align__(16) unsigned short As[BM * 64];   // 16 KB
  __shared__ __align__(16) unsigned short Bs[BN * 64];   // 32 KB
  const int tid = threadIdx.x;
  const int nby = gridDim.y;
  const int lin = (blockIdx.z * nby + blockIdx.y) * NBX + blockIdx.x;
  const int total = NBX * nby * KSPLIT;
  const int newlin = (lin & 7) * (total >> 3) + (lin >> 3);
  const int bx = newlin / (nby * KSPLIT);
  const int rem = newlin % (nby * KSPLIT);
  const int by = rem % nby;
  const int kz = rem / nby;
  const int rowbase = by * BM;
  if (rowbase >= off[8]) return;
  int e = 0;
#pragma unroll
  for (int i = 1; i <= 7; ++i) if (rowbase >= off[i]) e = i;
  const int n0 = bx * BN;
  const int k0base = kz * KS;
  const int wave = tid >> 6, lane = tid & 63;
  const int wm = wave >> 2, wn = wave & 3;
  const float* Wn0 = W + (size_t)e * K_ * N_ + n0;

  // A: 128x64 bf16 = 1024 16B-chunks, 2 per thread; pre-swizzled src (key row&7)
  const unsigned short* aSrc[2];
#pragma unroll
  for (int c = 0; c < 2; ++c) {
    int ca = (wave * 2 + c) * 64 + lane;
    int row = ca >> 3, slot = ca & 7;
    int sc = slot ^ (row & 7);
    aSrc[c] = A + (size_t)(rowbase + row) * K_ + k0base + sc * 8;
  }

  const int nq = lane & 15;
  const int qg = lane >> 4;
  const int kq = (qg & 1) * 4;
  fx4 br[GRP][4];

  fx4 acc[FM][FN];
#pragma unroll
  for (int a = 0; a < FM; ++a)
#pragma unroll
    for (int b = 0; b < FN; ++b) acc[a][b] = (fx4){0.f, 0.f, 0.f, 0.f};

  for (int t = 0; t < NT; ++t) {
    const int kt = t * BK;
    // ---- stage phase: A DMA + B fp32->bf16 reg-stage ----
#pragma unroll
    for (int c = 0; c < 2; ++c)
      load_lds16(aSrc[c] + kt, As + (wave * 2 + c) * 512);
#pragma unroll
    for (int g = 0; g < GRP; ++g) {
      const int cb = g * 2 + (qg >> 1);
#pragma unroll
      for (int j = 0; j < 4; ++j)
        br[g][j] = *(const fx4*)(Wn0 + (size_t)(kt + wave * 8 + kq + j) * N_ +
                                 cb * 64 + nq * 4);
    }
#pragma unroll
    for (int g = 0; g < GRP; ++g) {
      const int cb = g * 2 + (qg >> 1);
#pragma unroll
      for (int i = 0; i < 4; ++i) {
        const int nl = cb * 64 + nq * 4 + i;
        const int key = ((nl >> 2) + 2 * (nl & 3)) & 7;
        uint32_t d0 = cvtpk_bf16(br[g][0][i], br[g][1][i]);
        uint32_t d1 = cvtpk_bf16(br[g][2][i], br[g][3][i]);
        *(uint2*)(Bs + nl * 64 + (wave ^ key) * 8 + kq) = make_uint2(d0, d1);
      }
    }
    __syncthreads();   // drain A-DMA + B ds_writes (compiler-managed)
    // ---- compute phase: 32 MFMA/wave ----
#pragma unroll
    for (int kk = 0; kk < 2; ++kk) {
      bfx8 af[FM], bf[FN];
#pragma unroll
      for (int fm = 0; fm < FM; ++fm) {
        int r = wm * 64 + fm * 16 + (lane & 15);
        int c = (kk * 4 + (lane >> 4)) ^ (r & 7);
        af[fm] = *(const bfx8*)(As + r * 64 + c * 8);
      }
#pragma unroll
      for (int fn = 0; fn < FN; ++fn) {
        int nn = wn * 64 + fn * 16 + (lane & 15);
        int key = ((nn >> 2) + 2 * (nn & 3)) & 7;
        int c = (kk * 4 + (lane >> 4)) ^ key;
        bf[fn] = *(const bfx8*)(Bs + nn * 64 + c * 8);
      }
#pragma unroll
      for (int fm = 0; fm < FM; ++fm)
#pragma unroll
        for (int fn = 0; fn < FN; ++fn)
          acc[fm][fn] = __builtin_amdgcn_mfma_f32_16x16x32_bf16(
              af[fm], bf[fn], acc[fm][fn], 0, 0, 0);
    }
    __syncthreads();   // As/Bs free for next step
  }

  // ---- epilogue: coalesced fp32 partials ----
  const int colbase = n0 + wn * 64;
  float* Pk = Pout + (size_t)kz * RPMAX * N_;
#pragma unroll
  for (int fm = 0; fm < FM; ++fm) {
    int rg = rowbase + wm * 64 + fm * 16 + ((lane >> 4) << 2);
#pragma unroll
    for (int j = 0; j < 4; ++j) {
#pragma unroll
      for (int fn = 0; fn < FN; ++fn) {
        int colg = colbase + fn * 16 + (lane & 15);
        Pk[(size_t)(rg + j) * N_ + colg] = acc[fm][fn][j];
      }
    }
  }
}

extern "C" void kernel_launch(void* const* d_in, const int* in_sizes, int n_in,
                              void* d_out, int out_size, void* d_ws, size_t ws_size,
                              hipStream_t stream) {
  const float* x  = (const float*)d_in[0];
  const float* sw = (const float*)d_in[1];
  const float* sb = (const float*)d_in[2];
  const float* w1 = (const float*)d_in[3];
  const float* b1 = (const float*)d_in[4];
  const float* w2 = (const float*)d_in[5];
  const float* b2 = (const float*)d_in[6];
  float* out = (float*)d_out;

  char* ws = (char*)d_ws;
  int*   off      = (int*)(ws + 0);          // 9 ints
  int*   routes   = (int*)(ws + 1024);       // 2048 ints
  int*   perm_out = (int*)(ws + 16384);      // RPMAX ints (pads -1)
  int*   perm_src = (int*)(ws + 32768);      // RPMAX ints (pads 0)
  float* probs    = (float*)(ws + 65536);    // 2048x8 fp32
  unsigned short* xbf = (unsigned short*)(ws + (1u << 20));   // 4 MB
  unsigned short* H   = (unsigned short*)(ws + (8u << 20));   // 32 MB
  unsigned short* xg  = (unsigned short*)(ws + (40u << 20));  // 8 MB
  float* P            = (float*)(ws + (48u << 20));           // 64 MB

  // d_out layout: final(2097152) | counts(8) | psums(8) | 0(1) | pmax(2048)
  float* out_final  = out;
  float* out_counts = out + 2097152;
  float* out_psums  = out + 2097160;
  float* out_zero   = out + 2097168;
  float* out_pmax   = out + 2097169;

  router_kernel<<<T_TOK / 4, 256, 0, stream>>>(x, sw, sb, out_pmax, routes, probs, xbf);
  plan_kernel<<<1, 256, 0, stream>>>(routes, probs, off, perm_out, perm_src,
                                     out_counts, out_psums, out_zero);
  gather_kernel<<<RPMAX / 4, 256, 0, stream>>>(xbf, off, perm_src, xg);

  // GEMM1: xg[RP,1024] x W1 -> H (relu, bf16). 256x256 2-phase, grid 16x16=256.
  gemm256<256, D_DIM, F_DIM, 1, true>
      <<<dim3(F_DIM / 256, RPMAX / 256, 1), 512, 0, stream>>>(
          xg, w1, b1, off, H, nullptr);
  // GEMM2: H[RP,4096] x W2 -> fp32 partials P[4][RP][1024]. 128x256 single-buffer
  // (48 KB LDS, 2 blocks/CU), split-K=4, grid 4x32x4=512 blocks (2/CU exact).
  gemm2s<F_DIM, D_DIM, 4>
      <<<dim3(D_DIM / 256, RPMAX / 128, 4), 512, 0, stream>>>(H, w2, off, P);
  // reduce: out[tok] = (sum_kz P + b2[e]) * pmax[tok], coalesced scatter.
  reduce_kernel<<<RPMAX, 256, 0, stream>>>(P, off, perm_out, b2, out_pmax, out_final);
}

// Round 19
// 131.288 us; speedup vs baseline: 1.4204x; 1.0105x over previous
//
#include <hip/hip_runtime.h>
#include <stdint.h>

// Problem constants (B=2,S=1024,D=1024,F=4096,E=8)
#define T_TOK 2048
#define D_DIM 1024
#define F_DIM 4096
#define E_NUM 8
#define RPMAX 4096   // max padded rows at 256-alignment
#define BK 64

typedef __attribute__((ext_vector_type(8))) short bfx8;   // 8 bf16 (4 VGPR)
typedef __attribute__((ext_vector_type(4))) float fx4;    // MFMA accum / staging

__device__ __forceinline__ unsigned short f2bf(float f) {
  union { float f; uint32_t u; } v; v.f = f;
  uint32_t u = v.u;
  u += 0x7FFFu + ((u >> 16) & 1u);   // round-to-nearest-even
  return (unsigned short)(u >> 16);
}

__device__ __forceinline__ void load_lds16(const unsigned short* g, unsigned short* l) {
  __builtin_amdgcn_global_load_lds(
      (const __attribute__((address_space(1))) void*)g,
      (__attribute__((address_space(3))) void*)l, 16, 0, 0);
}

__device__ __forceinline__ uint32_t cvtpk_bf16(float lo, float hi) {
  uint32_t d;
  asm("v_cvt_pk_bf16_f32 %0, %1, %2" : "=v"(d) : "v"(lo), "v"(hi));
  return d;
}

// ---------------- router: logits, softmax, argmax; NO global atomics ----------------
__global__ __launch_bounds__(256) void router_kernel(
    const float* __restrict__ x, const float* __restrict__ sw,
    const float* __restrict__ sb, float* __restrict__ pmax_out,
    int* __restrict__ routes, float* __restrict__ probs,
    unsigned short* __restrict__ xbf) {
  const int wave = threadIdx.x >> 6, lane = threadIdx.x & 63;
  const int t = blockIdx.x * 4 + wave;
  const float* xr = x + (size_t)t * D_DIM;
  float acc[8];
#pragma unroll
  for (int e = 0; e < 8; ++e) acc[e] = 0.f;
#pragma unroll
  for (int i = 0; i < 4; ++i) {
    const int d = i * 256 + lane * 4;
    float4 xv = *(const float4*)(xr + d);
    ushort4 h;
    h.x = f2bf(xv.x); h.y = f2bf(xv.y); h.z = f2bf(xv.z); h.w = f2bf(xv.w);
    *(ushort4*)(xbf + (size_t)t * D_DIM + d) = h;
    const float xs[4] = {xv.x, xv.y, xv.z, xv.w};
#pragma unroll
    for (int j = 0; j < 4; ++j) {
      const float4* swp = (const float4*)(sw + (size_t)(d + j) * 8);
      float4 w0 = swp[0], w1 = swp[1];
      acc[0] += xs[j] * w0.x; acc[1] += xs[j] * w0.y;
      acc[2] += xs[j] * w0.z; acc[3] += xs[j] * w0.w;
      acc[4] += xs[j] * w1.x; acc[5] += xs[j] * w1.y;
      acc[6] += xs[j] * w1.z; acc[7] += xs[j] * w1.w;
    }
  }
#pragma unroll
  for (int e = 0; e < 8; ++e) {
    float v = acc[e];
    for (int o = 32; o > 0; o >>= 1) v += __shfl_down(v, o, 64);
    acc[e] = v;
  }
  if (lane == 0) {
#pragma unroll
    for (int e = 0; e < 8; ++e) acc[e] += sb[e];
    int am = 0; float mx = acc[0];
#pragma unroll
    for (int e = 1; e < 8; ++e) if (acc[e] > mx) { mx = acc[e]; am = e; }  // first-max wins
    float p[8]; float s = 0.f;
#pragma unroll
    for (int e = 0; e < 8; ++e) { p[e] = expf(acc[e] - mx); s += p[e]; }
    float inv = 1.0f / s;
    pmax_out[t] = inv;
    routes[t] = am;
#pragma unroll
    for (int e = 0; e < 8; ++e) probs[(size_t)t * 8 + e] = p[e] * inv;
  }
}

// -------- plan: counts/psums reduce, 256-aligned offsets, perm init, scatter --------
__global__ __launch_bounds__(256) void plan_kernel(
    const int* __restrict__ routes, const float* __restrict__ probs,
    int* __restrict__ off, int* __restrict__ perm_out, int* __restrict__ perm_src,
    float* __restrict__ out_counts, float* __restrict__ out_psums,
    float* __restrict__ out_zero) {
  __shared__ int cnt[8];
  __shared__ int cur[8];
  __shared__ int offs[9];
  __shared__ float red[256][8];
  const int tid = threadIdx.x;
  if (tid < 8) cnt[tid] = 0;
  for (int i = tid; i < RPMAX; i += 256) { perm_out[i] = -1; perm_src[i] = 0; }
  __syncthreads();
  float loc[8];
#pragma unroll
  for (int e = 0; e < 8; ++e) loc[e] = 0.f;
  for (int t = tid; t < T_TOK; t += 256) {
    atomicAdd(&cnt[routes[t]], 1);
    const float4* p = (const float4*)(probs + (size_t)t * 8);
    float4 a = p[0], b = p[1];
    loc[0] += a.x; loc[1] += a.y; loc[2] += a.z; loc[3] += a.w;
    loc[4] += b.x; loc[5] += b.y; loc[6] += b.z; loc[7] += b.w;
  }
#pragma unroll
  for (int e = 0; e < 8; ++e) red[tid][e] = loc[e];
  __syncthreads();
  for (int s = 128; s >= 1; s >>= 1) {
    if (tid < s) {
#pragma unroll
      for (int e = 0; e < 8; ++e) red[tid][e] += red[tid + s][e];
    }
    __syncthreads();
  }
  if (tid == 0) {
    int o = 0;
    for (int e = 0; e < 8; ++e) { offs[e] = o; o += ((cnt[e] + 255) >> 8) << 8; }
    offs[8] = o;
    *out_zero = 0.0f;
  }
  __syncthreads();
  if (tid < 9) off[tid] = offs[tid];
  if (tid < 8) {
    cur[tid] = offs[tid];
    out_counts[tid] = (float)cnt[tid];
    out_psums[tid] = red[0][tid];
  }
  __syncthreads();
  for (int t = tid; t < T_TOK; t += 256) {
    int e = routes[t];
    int pos = atomicAdd(&cur[e], 1);
    perm_out[pos] = t;
    perm_src[pos] = t;
  }
}

// ---------------- gather: xg[slot] = xbf[perm_src[slot]] ----------------
__global__ __launch_bounds__(256) void gather_kernel(
    const unsigned short* __restrict__ xbf, const int* __restrict__ off,
    const int* __restrict__ perm_src, unsigned short* __restrict__ xg) {
  const int wave = threadIdx.x >> 6, lane = threadIdx.x & 63;
  const int row = blockIdx.x * 4 + wave;
  if (row >= off[8]) return;
  const int tok = perm_src[row];
  const bfx8* s = (const bfx8*)(xbf + (size_t)tok * D_DIM);
  bfx8* d = (bfx8*)(xg + (size_t)row * D_DIM);
  d[lane] = s[lane];
  d[lane + 64] = s[lane + 64];
}

// ---------------- reduce: out[tok] = (sum_kz P[kz][row] + b2[e]) * pmax[tok] ----------
__global__ __launch_bounds__(256) void reduce_kernel(
    const float* __restrict__ P, const int* __restrict__ off,
    const int* __restrict__ perm_out, const float* __restrict__ b2,
    const float* __restrict__ pmax, float* __restrict__ out) {
  const int row = blockIdx.x;
  if (row >= off[8]) return;
  const int tok = perm_out[row];
  if (tok < 0) return;
  int e = 0;
#pragma unroll
  for (int i = 1; i <= 7; ++i) if (row >= off[i]) e = i;
  const int col = threadIdx.x * 4;
  const size_t base = (size_t)row * D_DIM + col;
  float4 p0 = *(const float4*)(P + base);
  float4 p1 = *(const float4*)(P + (size_t)1 * RPMAX * D_DIM + base);
  float4 p2 = *(const float4*)(P + (size_t)2 * RPMAX * D_DIM + base);
  float4 p3 = *(const float4*)(P + (size_t)3 * RPMAX * D_DIM + base);
  float4 bv = *(const float4*)(b2 + (size_t)e * D_DIM + col);
  const float pm = pmax[tok];
  float4 r;
  r.x = (p0.x + p1.x + p2.x + p3.x + bv.x) * pm;
  r.y = (p0.y + p1.y + p2.y + p3.y + bv.y) * pm;
  r.z = (p0.z + p1.z + p2.z + p3.z + bv.z) * pm;
  r.w = (p0.w + p1.w + p2.w + p3.w + bv.w) * pm;
  *(float4*)(out + (size_t)tok * D_DIM + col) = r;
}

// ---------------- GEMM1: 128x256 single-buffer, 48KB LDS, 2 blocks/CU ----------------
// Same structure as gemm2s (the ~4x winner in R18): 8 waves (2m x 4n), wave 64x64,
// m97 loop (STAGE -> barrier -> COMPUTE -> barrier); co-resident sibling block's
// COMPUTE hides the exposed memory phases (m114). A=xg bf16 DMA; B=W1 fp32 ->
// cvt_pk bf16 -> swizzled ds_write. Epilogue: relu(acc+b1) -> H bf16.
template <int K_, int N_>
__global__ __launch_bounds__(512, 4) void gemm1s(
    const unsigned short* __restrict__ A,    // xg [RP][K_]
    const float* __restrict__ W,             // [E][K_][N_] fp32
    const float* __restrict__ Bias,          // [E][N_]
    const int* __restrict__ off,
    unsigned short* __restrict__ Hout) {
  constexpr int BM = 128, BN = 256;
  constexpr int NT = K_ / BK;                // 16
  constexpr int FM = 4, FN = 4, GRP = 2;
  constexpr int NBX = N_ / BN;               // 16
  __shared__ __align__(16) unsigned short As[BM * 64];   // 16 KB
  __shared__ __align__(16) unsigned short Bs[BN * 64];   // 32 KB
  const int tid = threadIdx.x;
  const int nby = gridDim.y;
  const int lin = blockIdx.y * NBX + blockIdx.x;
  const int total = NBX * nby;
  const int newlin = (lin & 7) * (total >> 3) + (lin >> 3);
  const int bx = newlin / nby;
  const int by = newlin % nby;
  const int rowbase = by * BM;
  if (rowbase >= off[8]) return;
  int e = 0;
#pragma unroll
  for (int i = 1; i <= 7; ++i) if (rowbase >= off[i]) e = i;
  const int n0 = bx * BN;
  const int wave = tid >> 6, lane = tid & 63;
  const int wm = wave >> 2, wn = wave & 3;
  const float* Wn0 = W + (size_t)e * K_ * N_ + n0;

  const unsigned short* aSrc[2];
#pragma unroll
  for (int c = 0; c < 2; ++c) {
    int ca = (wave * 2 + c) * 64 + lane;
    int row = ca >> 3, slot = ca & 7;
    int sc = slot ^ (row & 7);
    aSrc[c] = A + (size_t)(rowbase + row) * K_ + sc * 8;
  }

  const int nq = lane & 15;
  const int qg = lane >> 4;
  const int kq = (qg & 1) * 4;
  fx4 br[GRP][4];

  fx4 acc[FM][FN];
#pragma unroll
  for (int a = 0; a < FM; ++a)
#pragma unroll
    for (int b = 0; b < FN; ++b) acc[a][b] = (fx4){0.f, 0.f, 0.f, 0.f};

  for (int t = 0; t < NT; ++t) {
    const int kt = t * BK;
#pragma unroll
    for (int c = 0; c < 2; ++c)
      load_lds16(aSrc[c] + kt, As + (wave * 2 + c) * 512);
#pragma unroll
    for (int g = 0; g < GRP; ++g) {
      const int cb = g * 2 + (qg >> 1);
#pragma unroll
      for (int j = 0; j < 4; ++j)
        br[g][j] = *(const fx4*)(Wn0 + (size_t)(kt + wave * 8 + kq + j) * N_ +
                                 cb * 64 + nq * 4);
    }
#pragma unroll
    for (int g = 0; g < GRP; ++g) {
      const int cb = g * 2 + (qg >> 1);
#pragma unroll
      for (int i = 0; i < 4; ++i) {
        const int nl = cb * 64 + nq * 4 + i;
        const int key = ((nl >> 2) + 2 * (nl & 3)) & 7;
        uint32_t d0 = cvtpk_bf16(br[g][0][i], br[g][1][i]);
        uint32_t d1 = cvtpk_bf16(br[g][2][i], br[g][3][i]);
        *(uint2*)(Bs + nl * 64 + (wave ^ key) * 8 + kq) = make_uint2(d0, d1);
      }
    }
    __syncthreads();
#pragma unroll
    for (int kk = 0; kk < 2; ++kk) {
      bfx8 af[FM], bf[FN];
#pragma unroll
      for (int fm = 0; fm < FM; ++fm) {
        int r = wm * 64 + fm * 16 + (lane & 15);
        int c = (kk * 4 + (lane >> 4)) ^ (r & 7);
        af[fm] = *(const bfx8*)(As + r * 64 + c * 8);
      }
#pragma unroll
      for (int fn = 0; fn < FN; ++fn) {
        int nn = wn * 64 + fn * 16 + (lane & 15);
        int key = ((nn >> 2) + 2 * (nn & 3)) & 7;
        int c = (kk * 4 + (lane >> 4)) ^ key;
        bf[fn] = *(const bfx8*)(Bs + nn * 64 + c * 8);
      }
#pragma unroll
      for (int fm = 0; fm < FM; ++fm)
#pragma unroll
        for (int fn = 0; fn < FN; ++fn)
          acc[fm][fn] = __builtin_amdgcn_mfma_f32_16x16x32_bf16(
              af[fm], bf[fn], acc[fm][fn], 0, 0, 0);
    }
    __syncthreads();
  }

  // ---- epilogue: relu(acc + b1) -> H bf16 ----
  const int colbase = n0 + wn * 64;
#pragma unroll
  for (int fn = 0; fn < FN; ++fn) {
    int colg = colbase + fn * 16 + (lane & 15);
    float bv = Bias[(size_t)e * N_ + colg];
#pragma unroll
    for (int fm = 0; fm < FM; ++fm) {
      int rg = rowbase + wm * 64 + fm * 16 + ((lane >> 4) << 2);
#pragma unroll
      for (int j = 0; j < 4; ++j) {
        float v = fmaxf(acc[fm][fn][j] + bv, 0.f);
        Hout[(size_t)(rg + j) * N_ + colg] = f2bf(v);
      }
    }
  }
}

// ---------------- GEMM2: 128x256 single-buffer, 48KB LDS, 2 blocks/CU (R18) ---------
template <int K_, int N_, int KSPLIT>
__global__ __launch_bounds__(512, 4) void gemm2s(
    const unsigned short* __restrict__ A,    // H [RP][K_]
    const float* __restrict__ W,             // [E][K_][N_] fp32
    const int* __restrict__ off,
    float* __restrict__ Pout) {
  constexpr int BM = 128, BN = 256;
  constexpr int KS = K_ / KSPLIT;
  constexpr int NT = KS / BK;
  constexpr int FM = 4, FN = 4, GRP = 2;
  constexpr int NBX = N_ / BN;
  __shared__ __align__(16) unsigned short As[BM * 64];   // 16 KB
  __shared__ __align__(16) unsigned short Bs[BN * 64];   // 32 KB
  const int tid = threadIdx.x;
  const int nby = gridDim.y;
  const int lin = (blockIdx.z * nby + blockIdx.y) * NBX + blockIdx.x;
  const int total = NBX * nby * KSPLIT;
  const int newlin = (lin & 7) * (total >> 3) + (lin >> 3);
  const int bx = newlin / (nby * KSPLIT);
  const int rem = newlin % (nby * KSPLIT);
  const int by = rem % nby;
  const int kz = rem / nby;
  const int rowbase = by * BM;
  if (rowbase >= off[8]) return;
  int e = 0;
#pragma unroll
  for (int i = 1; i <= 7; ++i) if (rowbase >= off[i]) e = i;
  const int n0 = bx * BN;
  const int k0base = kz * KS;
  const int wave = tid >> 6, lane = tid & 63;
  const int wm = wave >> 2, wn = wave & 3;
  const float* Wn0 = W + (size_t)e * K_ * N_ + n0;

  const unsigned short* aSrc[2];
#pragma unroll
  for (int c = 0; c < 2; ++c) {
    int ca = (wave * 2 + c) * 64 + lane;
    int row = ca >> 3, slot = ca & 7;
    int sc = slot ^ (row & 7);
    aSrc[c] = A + (size_t)(rowbase + row) * K_ + k0base + sc * 8;
  }

  const int nq = lane & 15;
  const int qg = lane >> 4;
  const int kq = (qg & 1) * 4;
  fx4 br[GRP][4];

  fx4 acc[FM][FN];
#pragma unroll
  for (int a = 0; a < FM; ++a)
#pragma unroll
    for (int b = 0; b < FN; ++b) acc[a][b] = (fx4){0.f, 0.f, 0.f, 0.f};

  for (int t = 0; t < NT; ++t) {
    const int kt = t * BK;
#pragma unroll
    for (int c = 0; c < 2; ++c)
      load_lds16(aSrc[c] + kt, As + (wave * 2 + c) * 512);
#pragma unroll
    for (int g = 0; g < GRP; ++g) {
      const int cb = g * 2 + (qg >> 1);
#pragma unroll
      for (int j = 0; j < 4; ++j)
        br[g][j] = *(const fx4*)(Wn0 + (size_t)(kt + wave * 8 + kq + j) * N_ +
                                 cb * 64 + nq * 4);
    }
#pragma unroll
    for (int g = 0; g < GRP; ++g) {
      const int cb = g * 2 + (qg >> 1);
#pragma unroll
      for (int i = 0; i < 4; ++i) {
        const int nl = cb * 64 + nq * 4 + i;
        const int key = ((nl >> 2) + 2 * (nl & 3)) & 7;
        uint32_t d0 = cvtpk_bf16(br[g][0][i], br[g][1][i]);
        uint32_t d1 = cvtpk_bf16(br[g][2][i], br[g][3][i]);
        *(uint2*)(Bs + nl * 64 + (wave ^ key) * 8 + kq) = make_uint2(d0, d1);
      }
    }
    __syncthreads();
#pragma unroll
    for (int kk = 0; kk < 2; ++kk) {
      bfx8 af[FM], bf[FN];
#pragma unroll
      for (int fm = 0; fm < FM; ++fm) {
        int r = wm * 64 + fm * 16 + (lane & 15);
        int c = (kk * 4 + (lane >> 4)) ^ (r & 7);
        af[fm] = *(const bfx8*)(As + r * 64 + c * 8);
      }
#pragma unroll
      for (int fn = 0; fn < FN; ++fn) {
        int nn = wn * 64 + fn * 16 + (lane & 15);
        int key = ((nn >> 2) + 2 * (nn & 3)) & 7;
        int c = (kk * 4 + (lane >> 4)) ^ key;
        bf[fn] = *(const bfx8*)(Bs + nn * 64 + c * 8);
      }
#pragma unroll
      for (int fm = 0; fm < FM; ++fm)
#pragma unroll
        for (int fn = 0; fn < FN; ++fn)
          acc[fm][fn] = __builtin_amdgcn_mfma_f32_16x16x32_bf16(
              af[fm], bf[fn], acc[fm][fn], 0, 0, 0);
    }
    __syncthreads();
  }

  const int colbase = n0 + wn * 64;
  float* Pk = Pout + (size_t)kz * RPMAX * N_;
#pragma unroll
  for (int fm = 0; fm < FM; ++fm) {
    int rg = rowbase + wm * 64 + fm * 16 + ((lane >> 4) << 2);
#pragma unroll
    for (int j = 0; j < 4; ++j) {
#pragma unroll
      for (int fn = 0; fn < FN; ++fn) {
        int colg = colbase + fn * 16 + (lane & 15);
        Pk[(size_t)(rg + j) * N_ + colg] = acc[fm][fn][j];
      }
    }
  }
}

extern "C" void kernel_launch(void* const* d_in, const int* in_sizes, int n_in,
                              void* d_out, int out_size, void* d_ws, size_t ws_size,
                              hipStream_t stream) {
  const float* x  = (const float*)d_in[0];
  const float* sw = (const float*)d_in[1];
  const float* sb = (const float*)d_in[2];
  const float* w1 = (const float*)d_in[3];
  const float* b1 = (const float*)d_in[4];
  const float* w2 = (const float*)d_in[5];
  const float* b2 = (const float*)d_in[6];
  float* out = (float*)d_out;

  char* ws = (char*)d_ws;
  int*   off      = (int*)(ws + 0);          // 9 ints
  int*   routes   = (int*)(ws + 1024);       // 2048 ints
  int*   perm_out = (int*)(ws + 16384);      // RPMAX ints (pads -1)
  int*   perm_src = (int*)(ws + 32768);      // RPMAX ints (pads 0)
  float* probs    = (float*)(ws + 65536);    // 2048x8 fp32
  unsigned short* xbf = (unsigned short*)(ws + (1u << 20));   // 4 MB
  unsigned short* H   = (unsigned short*)(ws + (8u << 20));   // 32 MB
  unsigned short* xg  = (unsigned short*)(ws + (40u << 20));  // 8 MB
  float* P            = (float*)(ws + (48u << 20));           // 64 MB

  // d_out layout: final(2097152) | counts(8) | psums(8) | 0(1) | pmax(2048)
  float* out_final  = out;
  float* out_counts = out + 2097152;
  float* out_psums  = out + 2097160;
  float* out_zero   = out + 2097168;
  float* out_pmax   = out + 2097169;

  router_kernel<<<T_TOK / 4, 256, 0, stream>>>(x, sw, sb, out_pmax, routes, probs, xbf);
  plan_kernel<<<1, 256, 0, stream>>>(routes, probs, off, perm_out, perm_src,
                                     out_counts, out_psums, out_zero);
  gather_kernel<<<RPMAX / 4, 256, 0, stream>>>(xbf, off, perm_src, xg);

  // GEMM1: xg[RP,1024] x W1 -> H (relu, bf16). 128x256 single-buffer, 48KB LDS,
  // grid 16x32=512 blocks (2/CU exact), n-chunked XCD swizzle.
  gemm1s<D_DIM, F_DIM>
      <<<dim3(F_DIM / 256, RPMAX / 128, 1), 512, 0, stream>>>(
          xg, w1, b1, off, H);
  // GEMM2: H[RP,4096] x W2 -> fp32 partials P[4][RP][1024]. 128x256 single-buffer,
  // split-K=4, grid 4x32x4=512 blocks (2/CU exact).
  gemm2s<F_DIM, D_DIM, 4>
      <<<dim3(D_DIM / 256, RPMAX / 128, 4), 512, 0, stream>>>(H, w2, off, P);
  // reduce: out[tok] = (sum_kz P + b2[e]) * pmax[tok], coalesced scatter.
  reduce_kernel<<<RPMAX, 256, 0, stream>>>(P, off, perm_out, b2, out_pmax, out_final);
}